// Round 4
// baseline (98.519 us; speedup 1.0000x reference)
//
#include <hip/hip_runtime.h>

#define WRR_GRID  2048   // 2048 blocks x 4 waves = 8192 waves = exactly full residency
#define WRR_BLOCK 256

// Per-block count of (x < y) over float4s; partial[blockIdx] written
// unconditionally every call -> no init/memset needed, no atomics.
__global__ __launch_bounds__(WRR_BLOCK) void wrr_count_kernel(
    const float4* __restrict__ x, const float4* __restrict__ y,
    unsigned int* __restrict__ partial, int iters, int rem) {
    const int tid    = blockIdx.x * WRR_BLOCK + threadIdx.x;
    const int stride = WRR_GRID * WRR_BLOCK;

    unsigned int c = 0;
    int i = tid;
    for (int j = 0; j < iters; ++j, i += stride) {
        float4 a = x[i];
        float4 b = y[i];
        c += (unsigned)(a.x < b.x) + (unsigned)(a.y < b.y) +
             (unsigned)(a.z < b.z) + (unsigned)(a.w < b.w);
    }
    // Uniform-iteration remainder: first `rem` threads take one extra element.
    if (tid < rem) {
        float4 a = x[i];
        float4 b = y[i];
        c += (unsigned)(a.x < b.x) + (unsigned)(a.y < b.y) +
             (unsigned)(a.z < b.z) + (unsigned)(a.w < b.w);
    }

    // Wave-64 reduce, then cross-wave via LDS.
    #pragma unroll
    for (int off = 32; off > 0; off >>= 1)
        c += __shfl_down(c, off);

    __shared__ unsigned int s[WRR_BLOCK / 64];
    if ((threadIdx.x & 63) == 0) s[threadIdx.x >> 6] = c;
    __syncthreads();
    if (threadIdx.x == 0)
        partial[blockIdx.x] = s[0] + s[1] + s[2] + s[3];
}

__global__ __launch_bounds__(256) void wrr_finalize_kernel(
    const unsigned int* __restrict__ partial, float* __restrict__ out,
    float inv_n) {
    unsigned int c = 0;
    for (int i = threadIdx.x; i < WRR_GRID; i += 256)
        c += partial[i];
    #pragma unroll
    for (int off = 32; off > 0; off >>= 1)
        c += __shfl_down(c, off);
    __shared__ unsigned int s[4];
    if ((threadIdx.x & 63) == 0) s[threadIdx.x >> 6] = c;
    __syncthreads();
    if (threadIdx.x == 0)
        out[0] = 1.0f - (float)(s[0] + s[1] + s[2] + s[3]) * inv_n;
}

extern "C" void kernel_launch(void* const* d_in, const int* in_sizes, int n_in,
                              void* d_out, int out_size, void* d_ws, size_t ws_size,
                              hipStream_t stream) {
    const float* x = (const float*)d_in[0];
    const float* y = (const float*)d_in[1];
    float* out = (float*)d_out;
    unsigned int* partial = (unsigned int*)d_ws;  // WRR_GRID uints, all written each call

    const long long n = (long long)in_sizes[0];  // 64,000,000 (divisible by 4)
    const int n4 = (int)(n / 4);
    const int threads = WRR_GRID * WRR_BLOCK;
    const int iters = n4 / threads;        // 30 for this shape
    const int rem   = n4 - iters * threads; // 271,360 for this shape

    wrr_count_kernel<<<WRR_GRID, WRR_BLOCK, 0, stream>>>(
        (const float4*)x, (const float4*)y, partial, iters, rem);
    wrr_finalize_kernel<<<1, 256, 0, stream>>>(partial, out, 1.0f / (float)n);
}

// Round 5
// 95.718 us; speedup vs baseline: 1.0293x; 1.0293x over previous
//
#include <hip/hip_runtime.h>

#define WRR_GRID  2048
#define WRR_BLOCK 256

// Each thread owns PAIRS of adjacent float4s (32 B per stream per iter).
// Manual 2-deep software pipeline: next iteration's 4 loads are issued
// before the current iteration's operands are consumed.
__global__ __launch_bounds__(WRR_BLOCK) void wrr_count_kernel(
    const float4* __restrict__ x, const float4* __restrict__ y,
    unsigned int* __restrict__ partial, int iters, int rem) {
    const int tid    = blockIdx.x * WRR_BLOCK + threadIdx.x;
    const int stride = WRR_GRID * WRR_BLOCK;   // in pairs

    unsigned int c = 0;
    long long i4 = 2LL * tid;                  // float4 index of this thread's pair
    const long long step = 2LL * stride;

    // prologue: load pair 0
    float4 ax0 = x[i4], ax1 = x[i4 + 1];
    float4 ay0 = y[i4], ay1 = y[i4 + 1];

    for (int j = 0; j < iters - 1; ++j) {
        const long long ni = i4 + step;
        // issue next iteration's loads first (4 in flight while consuming)
        float4 bx0 = x[ni], bx1 = x[ni + 1];
        float4 by0 = y[ni], by1 = y[ni + 1];

        c += (unsigned)(ax0.x < ay0.x) + (unsigned)(ax0.y < ay0.y) +
             (unsigned)(ax0.z < ay0.z) + (unsigned)(ax0.w < ay0.w);
        c += (unsigned)(ax1.x < ay1.x) + (unsigned)(ax1.y < ay1.y) +
             (unsigned)(ax1.z < ay1.z) + (unsigned)(ax1.w < ay1.w);

        ax0 = bx0; ax1 = bx1; ay0 = by0; ay1 = by1;
        i4 = ni;
    }
    // epilogue: consume last pipelined pair
    c += (unsigned)(ax0.x < ay0.x) + (unsigned)(ax0.y < ay0.y) +
         (unsigned)(ax0.z < ay0.z) + (unsigned)(ax0.w < ay0.w);
    c += (unsigned)(ax1.x < ay1.x) + (unsigned)(ax1.y < ay1.y) +
         (unsigned)(ax1.z < ay1.z) + (unsigned)(ax1.w < ay1.w);

    // remainder: first `rem` threads take one extra pair
    if (tid < rem) {
        const long long ni = i4 + step;
        float4 bx0 = x[ni], bx1 = x[ni + 1];
        float4 by0 = y[ni], by1 = y[ni + 1];
        c += (unsigned)(bx0.x < by0.x) + (unsigned)(bx0.y < by0.y) +
             (unsigned)(bx0.z < by0.z) + (unsigned)(bx0.w < by0.w);
        c += (unsigned)(bx1.x < by1.x) + (unsigned)(bx1.y < by1.y) +
             (unsigned)(bx1.z < by1.z) + (unsigned)(bx1.w < by1.w);
    }

    // Wave-64 reduce, then cross-wave via LDS.
    #pragma unroll
    for (int off = 32; off > 0; off >>= 1)
        c += __shfl_down(c, off);

    __shared__ unsigned int s[WRR_BLOCK / 64];
    if ((threadIdx.x & 63) == 0) s[threadIdx.x >> 6] = c;
    __syncthreads();
    if (threadIdx.x == 0)
        partial[blockIdx.x] = s[0] + s[1] + s[2] + s[3];
}

__global__ __launch_bounds__(256) void wrr_finalize_kernel(
    const unsigned int* __restrict__ partial, float* __restrict__ out,
    float inv_n) {
    unsigned int c = 0;
    for (int i = threadIdx.x; i < WRR_GRID; i += 256)
        c += partial[i];
    #pragma unroll
    for (int off = 32; off > 0; off >>= 1)
        c += __shfl_down(c, off);
    __shared__ unsigned int s[4];
    if ((threadIdx.x & 63) == 0) s[threadIdx.x >> 6] = c;
    __syncthreads();
    if (threadIdx.x == 0)
        out[0] = 1.0f - (float)(s[0] + s[1] + s[2] + s[3]) * inv_n;
}

extern "C" void kernel_launch(void* const* d_in, const int* in_sizes, int n_in,
                              void* d_out, int out_size, void* d_ws, size_t ws_size,
                              hipStream_t stream) {
    const float* x = (const float*)d_in[0];
    const float* y = (const float*)d_in[1];
    float* out = (float*)d_out;
    unsigned int* partial = (unsigned int*)d_ws;  // WRR_GRID uints, all written each call

    const long long n = (long long)in_sizes[0];  // 64,000,000 (divisible by 8)
    const int npairs = (int)(n / 8);             // pairs of float4s
    const int threads = WRR_GRID * WRR_BLOCK;
    const int iters = npairs / threads;          // 15 for this shape
    const int rem   = npairs - iters * threads;  // 135,680 for this shape

    wrr_count_kernel<<<WRR_GRID, WRR_BLOCK, 0, stream>>>(
        (const float4*)x, (const float4*)y, partial, iters, rem);
    wrr_finalize_kernel<<<1, 256, 0, stream>>>(partial, out, 1.0f / (float)n);
}